// Round 2
// baseline (463.957 us; speedup 1.0000x reference)
//
#include <hip/hip_runtime.h>
#include <hip/hip_bf16.h>
#include <stdint.h>

// Problem constants: M=512, P=256, B=128, T=1024
#define NB   128
#define NT   1024
#define NM   512
#define NP   256

typedef __attribute__((ext_vector_type(8))) short bf16x8;
typedef __attribute__((ext_vector_type(4))) float f32x4;
typedef unsigned int u32;

// pack two f32 -> two bf16 in one u32 (round-half-up; bias << bf16 ulp)
__device__ __forceinline__ uint32_t bfpair(float a, float b) {
    uint32_t ua = __float_as_uint(a) + 0x8000u;
    uint32_t ub = __float_as_uint(b) + 0x8000u;
    return __builtin_amdgcn_perm(ub, ua, 0x07060302u);
}

__device__ __forceinline__ float fast_tanh(float x) {
    float e = __expf(2.0f * x);                       // inf-safe
    return 1.0f - 2.0f * __builtin_amdgcn_rcpf(e + 1.0f);
}

// async global->LDS DMA, 16 B per lane; LDS dest = wave-uniform base + lane*16
typedef const __attribute__((address_space(1))) u32* gas_t;
typedef __attribute__((address_space(3))) u32* las_t;
__device__ __forceinline__ void dma16(const void* g, void* l) {
    __builtin_amdgcn_global_load_lds((gas_t)g, (las_t)l, 16, 0, 0);
}

// ---------- prep: 0..255 cvt U->bf16 | 256..383 wq GEMV | 384..511 zero d_out ----------
__global__ void prep_kernel(const float* __restrict__ U, unsigned short* __restrict__ Ub,
                            const float* __restrict__ d_t, const float* __restrict__ s_t,
                            const float* __restrict__ W, float* __restrict__ wq,
                            float* __restrict__ out) {
    const int bx = blockIdx.x;
    if (bx < 256) {
        int idx = bx * 256 + threadIdx.x;                  // 65536 threads, 1 float4 each
        float4 u = reinterpret_cast<const float4*>(U)[idx];
        reinterpret_cast<uint2*>(Ub)[idx] = make_uint2(bfpair(u.x, u.y), bfpair(u.z, u.w));
    } else if (bx < 384) {
        int g = (bx - 256) * 512 + threadIdx.x * 2;        // 2 outputs/thread -> 65536
        int b = g >> 9;
        const float* dt = d_t + (size_t)b * NP;
        const float* st = s_t + (size_t)b * NP;
        #pragma unroll
        for (int e = 0; e < 2; ++e) {
            int n = (g + e) & 511;
            const float* Wn = W + (size_t)n * 512;
            float s = 0.f;
            #pragma unroll 4
            for (int c = 0; c < NP; c += 4) {
                float4 w0 = *reinterpret_cast<const float4*>(Wn + c);
                float4 q0 = *reinterpret_cast<const float4*>(dt + c);
                s += w0.x * q0.x + w0.y * q0.y + w0.z * q0.z + w0.w * q0.w;
                float4 w1 = *reinterpret_cast<const float4*>(Wn + NP + c);
                float4 q1 = *reinterpret_cast<const float4*>(st + c);
                s += w1.x * q1.x + w1.y * q1.y + w1.z * q1.z + w1.w * q1.w;
            }
            wq[g + e] = s;
        }
    } else {
        int idx = (bx - 384) * 256 + threadIdx.x;          // 32768 float4 = 128K floats
        reinterpret_cast<float4*>(out)[idx] = make_float4(0.f, 0.f, 0.f, 0.f);
    }
}

// ---------- score: 128t x 256n per WG, 512 threads (8 waves), wave tile 64x64 ----------
// grid 2048 1-D, swizzled: tile=(id>>4)*8+(id&7), nh=(id>>3)&1 -> nh pair on same XCD.
// v3: occupancy push. acc = 4x4 f32x4 = 64 AGPR/thread; __launch_bounds__(512,4) caps
// unified regs at 128 -> 2 blocks x 8 waves = 16 waves/CU = 4 waves/SIMD (was 2).
// Rolled loop (#pragma unroll 1): hot body stays in L1I.
// Pipeline: B via global_load_lds, 3 rotating bufs, depth-2, vmcnt(2) at barrier (never 0).
//           A global->reg (issued early) -> cvt bf16 -> ds_write (late), As double-buf.
// LDS swizzle (both A and B, 64 B rows of 4x16B chunks): chunk c of row r at slot
// c ^ ((r>>1)&3); involution applied on write (A) / pre-swizzled DMA source (B) and read.
__global__ __launch_bounds__(512, 4)
void score_kernel(const float* __restrict__ H, const unsigned short* __restrict__ Ub,
                  const float* __restrict__ wq, const float* __restrict__ v_d,
                  float* __restrict__ out) {
    __shared__ unsigned short As[2][128 * 32];     //  8 KB/buf bf16, swizzled
    __shared__ unsigned short Bs[3][256 * 32];     // 16 KB/buf bf16, swizzled
    __shared__ float s_score[128];                 // total 66048 B -> 2 blocks/CU

    const int tid  = threadIdx.x;
    const int id   = blockIdx.x;
    const int tile = (id >> 4) * 8 + (id & 7);
    const int nh   = (id >> 3) & 1;
    const int tt   = tile & 7;
    const int b    = tile >> 3;

    const int lane = tid & 63;
    const int w    = tid >> 6;          // 0..7
    const int lr   = lane & 15;
    const int lq   = lane >> 4;
    const int tw   = w >> 2;            // 0..1  (t half)
    const int nw   = w & 3;             // 0..3  (n quarter)

    if (tid < 128) s_score[tid] = 0.f;

    // A staging: thread -> row rA = tid>>2, 16B-chunk uA = tid&3 (8 consecutive k-floats)
    const int rA = tid >> 2, uA = tid & 3;
    const float* gA = H + ((size_t)(b * NT + tt * 128 + rA)) * NM + uA * 8;
    const u32 woff = (u32)(rA * 64 + ((uA ^ ((rA >> 1) & 3)) << 4));

    // B DMA: wave w, q in {0,1}: rows w*32+q*16+(lane>>2); source chunk pre-swizzled
    const unsigned short* gB0, * gB1;
    u32 lB0, lB1;
    {
        int rB0 = w * 32 + (lane >> 2);
        int rB1 = rB0 + 16;
        gB0 = Ub + ((size_t)(nh * 256 + rB0)) * NM + (((lane & 3) ^ ((rB0 >> 1) & 3)) * 8);
        gB1 = Ub + ((size_t)(nh * 256 + rB1)) * NM + (((lane & 3) ^ ((rB1 >> 1) & 3)) * 8);
        lB0 = (u32)((w * 32) * 64 + lane * 16);
        lB1 = lB0 + 16 * 64;
    }

    // fragment read offsets (chunk lq of row, slot = lq ^ ((row>>1)&3)); +1024 B per frag
    const u32 aro = (u32)((tw * 64 + lr) * 64 + ((lq ^ ((lr >> 1) & 3)) << 4));
    const u32 bro = (u32)((nw * 64 + lr) * 64 + ((lq ^ ((lr >> 1) & 3)) << 4));

    f32x4 acc[4][4];
    #pragma unroll
    for (int i = 0; i < 4; ++i)
        #pragma unroll
        for (int j = 0; j < 4; ++j)
            acc[i][j] = (f32x4){0.f, 0.f, 0.f, 0.f};

    // ---- prologue: Aload(0) -> regs; dmaB(0)->Bs0; dmaB(1)->Bs1; write As[0] ----
    float4 av0 = *reinterpret_cast<const float4*>(gA);
    float4 av1 = *reinterpret_cast<const float4*>(gA + 4);
    gA += 32;
    dma16(gB0, (char*)Bs[0] + lB0);
    dma16(gB1, (char*)Bs[0] + lB1);
    gB0 += 32; gB1 += 32;
    dma16(gB0, (char*)Bs[1] + lB0);
    dma16(gB1, (char*)Bs[1] + lB1);
    gB0 += 32; gB1 += 32;
    {
        uint4 wv4;                                   // compiler inserts vmcnt wait for av
        wv4.x = bfpair(av0.x, av0.y); wv4.y = bfpair(av0.z, av0.w);
        wv4.z = bfpair(av1.x, av1.y); wv4.w = bfpair(av1.z, av1.w);
        *reinterpret_cast<uint4*>((char*)As[0] + woff) = wv4;
    }
    asm volatile("s_waitcnt vmcnt(2)" ::: "memory");   // B(0) landed; B(1) stays in flight
    asm volatile("s_waitcnt lgkmcnt(0)" ::: "memory");
    __builtin_amdgcn_s_barrier();
    __builtin_amdgcn_sched_barrier(0);

    u32 offA = 0;                                   // As read offset: 0 / 8192
    u32 rb0 = 0, rb1 = 16384, rb2 = 32768;          // Bs byte offsets: read / next / dma-target

    #pragma unroll 1
    for (int kk = 0; kk < 16; ++kk) {
        // A fragments for this k-chunk
        const char* ab = (const char*)As + offA + aro;
        bf16x8 a0 = *reinterpret_cast<const bf16x8*>(ab);
        bf16x8 a1 = *reinterpret_cast<const bf16x8*>(ab + 1024);
        bf16x8 a2 = *reinterpret_cast<const bf16x8*>(ab + 2048);
        bf16x8 a3 = *reinterpret_cast<const bf16x8*>(ab + 3072);

        // issue-early: next A chunk to regs, B(kk+2) DMA into rotating buffer
        float4 nv0, nv1;
        if (kk < 15) {
            nv0 = *reinterpret_cast<const float4*>(gA);
            nv1 = *reinterpret_cast<const float4*>(gA + 4);
            gA += 32;
        }
        if (kk < 14) {
            char* bwr = (char*)Bs + rb2;
            dma16(gB0, bwr + lB0);
            dma16(gB1, bwr + lB1);
            gB0 += 32; gB1 += 32;
        }

        // B fragments + MFMA (16 per wave per iter)
        const char* bb = (const char*)Bs + rb0 + bro;
        #pragma unroll
        for (int j = 0; j < 4; ++j) {
            bf16x8 bj = *reinterpret_cast<const bf16x8*>(bb + j * 1024);
            acc[0][j] = __builtin_amdgcn_mfma_f32_16x16x32_bf16(a0, bj, acc[0][j], 0, 0, 0);
            acc[1][j] = __builtin_amdgcn_mfma_f32_16x16x32_bf16(a1, bj, acc[1][j], 0, 0, 0);
            acc[2][j] = __builtin_amdgcn_mfma_f32_16x16x32_bf16(a2, bj, acc[2][j], 0, 0, 0);
            acc[3][j] = __builtin_amdgcn_mfma_f32_16x16x32_bf16(a3, bj, acc[3][j], 0, 0, 0);
        }

        if (kk < 15) {
            // write-late: A(kk+1) -> other As buffer (compiler waits vmcnt for nv,
            // which also drains the older dmaB(kk+1); dmaB(kk+2) stays in flight)
            char* an = (char*)As + (offA ^ 8192) + woff;
            uint4 wv4;
            wv4.x = bfpair(nv0.x, nv0.y); wv4.y = bfpair(nv0.z, nv0.w);
            wv4.z = bfpair(nv1.x, nv1.y); wv4.w = bfpair(nv1.z, nv1.w);
            *reinterpret_cast<uint4*>(an) = wv4;
            asm volatile("s_waitcnt vmcnt(2)" ::: "memory");   // never drain to 0 mid-loop
            asm volatile("s_waitcnt lgkmcnt(0)" ::: "memory");
            __builtin_amdgcn_s_barrier();
            __builtin_amdgcn_sched_barrier(0);
        }
        offA ^= 8192;
        u32 t = rb0; rb0 = rb1; rb1 = rb2; rb2 = t;
    }

    // epilogue: acc[i][j][r] at t = tt*128 + tw*64 + i*16 + lq*4 + r,
    //                         n = nh*256 + nw*64 + j*16 + lr
    const float* wqb = wq + (size_t)b * NM;
    float vv[4], wv[4];
    #pragma unroll
    for (int j = 0; j < 4; ++j) {
        int n = nh * 256 + nw * 64 + j * 16 + lr;
        vv[j] = v_d[n];
        wv[j] = wqb[n];
    }
    #pragma unroll
    for (int i = 0; i < 4; ++i) {
        #pragma unroll
        for (int r = 0; r < 4; ++r) {
            float s = 0.f;
            #pragma unroll
            for (int j = 0; j < 4; ++j)
                s += vv[j] * fast_tanh(wv[j] + acc[i][j][r]);
            #pragma unroll
            for (int off = 1; off < 16; off <<= 1)
                s += __shfl_xor(s, off, 64);
            if (lr == 0) atomicAdd(&s_score[tw * 64 + i * 16 + lq * 4 + r], s);
        }
    }
    __syncthreads();
    if (tid < 128) atomicAdd(&out[(size_t)b * NT + tt * 128 + tid], s_score[tid]);
}

// ---------- softmax over T=1024, in place, one WG per b ----------
__global__ void softmax_kernel(float* __restrict__ out) {
    const int b   = blockIdx.x;
    const int tid = threadIdx.x;          // 256 threads x 4 elems
    float* p = out + (size_t)b * NT;
    float4 v = reinterpret_cast<float4*>(p)[tid];
    float m = fmaxf(fmaxf(v.x, v.y), fmaxf(v.z, v.w));
    #pragma unroll
    for (int off = 32; off >= 1; off >>= 1)
        m = fmaxf(m, __shfl_xor(m, off, 64));
    __shared__ float red[8];
    const int wv = tid >> 6;
    if ((tid & 63) == 0) red[wv] = m;
    __syncthreads();
    m = fmaxf(fmaxf(red[0], red[1]), fmaxf(red[2], red[3]));
    float e0 = __expf(v.x - m), e1 = __expf(v.y - m);
    float e2 = __expf(v.z - m), e3 = __expf(v.w - m);
    float s = e0 + e1 + e2 + e3;
    #pragma unroll
    for (int off = 32; off >= 1; off >>= 1)
        s += __shfl_xor(s, off, 64);
    if ((tid & 63) == 0) red[4 + wv] = s;
    __syncthreads();
    s = red[4] + red[5] + red[6] + red[7];
    float inv = 1.f / s;
    float4 o;
    o.x = e0 * inv; o.y = e1 * inv; o.z = e2 * inv; o.w = e3 * inv;
    reinterpret_cast<float4*>(p)[tid] = o;
}

extern "C" void kernel_launch(void* const* d_in, const int* in_sizes, int n_in,
                              void* d_out, int out_size, void* d_ws, size_t ws_size,
                              hipStream_t stream) {
    const float* d_t = (const float*)d_in[0];
    const float* s_t = (const float*)d_in[1];
    const float* H   = (const float*)d_in[2];
    // d_in[3] = T (scalar, 1024) — shapes hard-coded
    const float* W_d = (const float*)d_in[4];
    const float* U_d = (const float*)d_in[5];
    const float* v_d = (const float*)d_in[6];
    float* out = (float*)d_out;

    unsigned short* Ub = (unsigned short*)d_ws;              // 512 KB bf16 U
    float* wq = (float*)((char*)d_ws + 512 * 1024);          // 256 KB fp32 wq

    prep_kernel<<<512, 256, 0, stream>>>(U_d, Ub, d_t, s_t, W_d, wq, out);
    score_kernel<<<2048, 512, 0, stream>>>(H, Ub, wq, v_d, out);
    softmax_kernel<<<NB, 256, 0, stream>>>(out);
}